// Round 1
// baseline (713.411 us; speedup 1.0000x reference)
//
#include <hip/hip_runtime.h>

// CombinedLoss: 0.7*MSE(pred,target) + 0.3*mean_b softDTW_gamma(pred,target)
// B=64, T=1024, C=8, fp32 in/out. One block per batch element; anti-diagonal
// wavefront DP with 3 rotating LDS rows (1 barrier per diagonal).

constexpr int BB = 64;
constexpr int TT = 1024;
constexpr int CC = 8;
constexpr float ALPHA_ = 0.7f;
constexpr float GAMMA_ = 0.2f;
constexpr float FINF = 1000000000.0f;

__global__ __launch_bounds__(1024) void sdtw_kernel(
    const float* __restrict__ pred, const float* __restrict__ target,
    float* __restrict__ ws)
{
    // LDS: 32K target(transposed) + 4K y2 + 12K DP rows + reduce scratch
    __shared__ float s_t[CC][TT];   // transposed: s_t[c][j] -> stride-1 in j
    __shared__ float s_y2[TT];
    __shared__ float s_r[3][TT];    // rotating km2 / km1 / new
    __shared__ float s_red[16];

    const int b = blockIdx.x;
    const int i = threadIdx.x;

    const float* pr = pred   + ((size_t)b * TT + i) * CC;
    const float* tr = target + ((size_t)b * TT + i) * CC;

    float4 pa = ((const float4*)pr)[0];
    float4 pb = ((const float4*)pr)[1];
    float4 ta = ((const float4*)tr)[0];
    float4 tb = ((const float4*)tr)[1];

    float p[CC] = {pa.x, pa.y, pa.z, pa.w, pb.x, pb.y, pb.z, pb.w};
    float t[CC] = {ta.x, ta.y, ta.z, ta.w, tb.x, tb.y, tb.z, tb.w};

    float x2 = 0.f, y2 = 0.f, msep = 0.f;
    #pragma unroll
    for (int c = 0; c < CC; ++c) {
        x2 = fmaf(p[c], p[c], x2);
        y2 = fmaf(t[c], t[c], y2);
        float d = p[c] - t[c];
        msep = fmaf(d, d, msep);
        s_t[c][i] = t[c];
    }
    s_y2[i]   = y2;
    s_r[0][i] = FINF;   // r_{k-2}
    s_r[1][i] = FINF;   // r_{k-1}

    // fused MSE partial: wave shuffle reduce then cross-wave via LDS
    #pragma unroll
    for (int off = 32; off > 0; off >>= 1)
        msep += __shfl_down(msep, off, 64);
    if ((i & 63) == 0) s_red[i >> 6] = msep;

    __syncthreads();
    if (i == 0) {
        float s = 0.f;
        #pragma unroll
        for (int w = 0; w < 16; ++w) s += s_red[w];
        ws[b] = s;   // partial sum of squared diffs for batch b
    }

    const float inv_g = 1.0f / GAMMA_;
    int ia = 0, ib = 1, ic = 2;   // km2, km1, new
    float rn = FINF;
    for (int k = 0; k < 2 * TT - 1; ++k) {
        __syncthreads();          // writes of iter k-1 visible; old km2 free
        float left = s_r[ib][i];
        float up   = (i > 0) ? s_r[ib][i - 1] : FINF;
        float dg   = (i > 0) ? s_r[ia][i - 1] : ((k == 0) ? 0.0f : FINF);
        int j = k - i;
        rn = FINF;
        if (j >= 0 && j < TT) {
            float dot = 0.f;
            #pragma unroll
            for (int c = 0; c < CC; ++c) dot = fmaf(p[c], s_t[c][j], dot);
            float Dv = x2 + s_y2[j] - 2.0f * dot;
            // softmin_gamma == -g*logsumexp(-x/g) with max-sub == min-sub
            float m = fminf(fminf(up, left), dg);
            float e = __expf((m - up)  * inv_g)
                    + __expf((m - left)* inv_g)
                    + __expf((m - dg)  * inv_g);
            rn = Dv + m - GAMMA_ * __logf(e);
        }
        s_r[ic][i] = rn;
        int tmp = ia; ia = ib; ib = ic; ic = tmp;
    }
    // last diagonal k=2T-2 is valid only at i=T-1 (j=T-1)
    if (i == TT - 1) ws[BB + b] = rn;
}

__global__ __launch_bounds__(64) void finalize_kernel(
    const float* __restrict__ ws, float* __restrict__ out)
{
    int t = threadIdx.x;          // 64 threads = 1 wave
    float mse = ws[t];
    float sd  = ws[BB + t];
    #pragma unroll
    for (int off = 32; off > 0; off >>= 1) {
        mse += __shfl_down(mse, off, 64);
        sd  += __shfl_down(sd,  off, 64);
    }
    if (t == 0) {
        float msev = mse / (float)((size_t)BB * TT * CC);
        float sdtw = sd  / (float)BB;
        out[0] = ALPHA_ * msev + (1.0f - ALPHA_) * sdtw;
    }
}

extern "C" void kernel_launch(void* const* d_in, const int* in_sizes, int n_in,
                              void* d_out, int out_size, void* d_ws, size_t ws_size,
                              hipStream_t stream) {
    const float* pred   = (const float*)d_in[0];
    const float* target = (const float*)d_in[1];
    float* ws  = (float*)d_ws;
    float* out = (float*)d_out;

    sdtw_kernel<<<BB, TT, 0, stream>>>(pred, target, ws);
    finalize_kernel<<<1, 64, 0, stream>>>(ws, out);
}